// Round 3
// baseline (503.603 us; speedup 1.0000x reference)
//
#include <hip/hip_runtime.h>
#include <math.h>

#define N_TOK 32768
#define IN_DIM 1024
#define HID 256
#define NE 64

// ---------------------------------------------------------------------------
// Pre-pass: W1[256][1024] -> W1T[1024][256] (1 MB in workspace).
// Lets phase A read a lane's 4-hidden fragment as one coalesced float4 from
// L2, killing all LDS staging/transpose in the hot GEMM.
// ---------------------------------------------------------------------------
__global__ __launch_bounds__(256)
void transpose_w1(const float* __restrict__ w1, float* __restrict__ w1t)
{
    __shared__ float tile[32][33];
    const int k0 = blockIdx.x * 32;
    const int h0 = blockIdx.y * 32;
    const int j  = threadIdx.x & 31;
    const int i0 = threadIdx.x >> 5;
    #pragma unroll
    for (int r = 0; r < 4; ++r) {
        int i = i0 + r * 8;
        tile[i][j] = w1[(size_t)(h0 + i) * IN_DIM + k0 + j];  // coalesced in k
    }
    __syncthreads();
    #pragma unroll
    for (int r = 0; r < 4; ++r) {
        int i = i0 + r * 8;
        w1t[(size_t)(k0 + i) * HID + h0 + j] = tile[j][i];    // coalesced in h
    }
}

// ---------------------------------------------------------------------------
// Fused gating network.
// Phase A (no LDS, no barriers): H = relu(X @ W1T + b1).
//   wave = 16 tokens x 256 hidden; lane = 16 tok x 4 hid; acc[16][4].
//   X: wave-uniform global_load_dwordx2 (1 request broadcast to 64 lanes),
//      double-buffered 2-k groups, prefetch distance 4k (~1024 cyc) > L3 lat.
//   W: per-lane contiguous float4 from W1T (L2-resident), double-buffered.
//   Per k: 1 VMEM W-load + 64 FMA. Round-2's 4 ds_read_b128/k oversubscribed
//   the per-CU LDS pipe 1.5x (VALUBusy capped at 56%); this removes it.
// Phase B: verbatim round-2 logits/top-2/softmax path; H handed off through
//   LDS in the exact same swizzled layout -> bit-identical outputs.
// ---------------------------------------------------------------------------
union SMem {
    struct { float Hs[128][64]; float W2s[32][64]; } b;  // 32K + 8K
    float Ls[64][67];                                    // 17K
};

__global__ __launch_bounds__(256, 2)
void moe_gate(const float* __restrict__ x,  const float* __restrict__ w1t,
              const float* __restrict__ b1, const float* __restrict__ w2,
              const float* __restrict__ b2, float* __restrict__ out)
{
    __shared__ SMem sm;

    const int tid = threadIdx.x;
    const int w   = tid >> 6;        // wave 0..3 -> tokens w*16 .. w*16+15
    const int l   = tid & 63;        // lane      -> hiddens l*4 .. l*4+3
    const int t0  = blockIdx.x * 64;

    const float* xb = x + (size_t)(t0 + w * 16) * IN_DIM;  // wave's 16 rows
    const float* wb = w1t + l * 4;                          // lane's h-quad col

    float acc[16][4];
    #pragma unroll
    for (int t = 0; t < 16; ++t)
        #pragma unroll
        for (int j = 0; j < 4; ++j) acc[t][j] = 0.f;

    // ---------------- phase A ----------------
    // double-buffered register pipeline over 512 groups of 2 k each
    float2 xA[16], xB[16];
    float4 wA0, wA1, wB0, wB1;
    #pragma unroll
    for (int t = 0; t < 16; ++t) xA[t] = *(const float2*)(xb + (size_t)t * IN_DIM + 0);
    #pragma unroll
    for (int t = 0; t < 16; ++t) xB[t] = *(const float2*)(xb + (size_t)t * IN_DIM + 2);
    wA0 = *(const float4*)(wb + 0 * HID);
    wA1 = *(const float4*)(wb + 1 * HID);
    wB0 = *(const float4*)(wb + 2 * HID);
    wB1 = *(const float4*)(wb + 3 * HID);

#define FMA_GROUP(XV, W0, W1)                                    \
    _Pragma("unroll")                                            \
    for (int t = 0; t < 16; ++t) {                               \
        acc[t][0] = fmaf(XV[t].x, W0.x, acc[t][0]);              \
        acc[t][1] = fmaf(XV[t].x, W0.y, acc[t][1]);              \
        acc[t][2] = fmaf(XV[t].x, W0.z, acc[t][2]);              \
        acc[t][3] = fmaf(XV[t].x, W0.w, acc[t][3]);              \
        acc[t][0] = fmaf(XV[t].y, W1.x, acc[t][0]);              \
        acc[t][1] = fmaf(XV[t].y, W1.y, acc[t][1]);              \
        acc[t][2] = fmaf(XV[t].y, W1.z, acc[t][2]);              \
        acc[t][3] = fmaf(XV[t].y, W1.w, acc[t][3]);              \
    }

    #pragma unroll 1
    for (int g = 0; g < 510; g += 2) {
        const int k = g * 2;                 // wA = w[k], w[k+1]; xA = k,k+1
        FMA_GROUP(xA, wA0, wA1)
        // refill A <- group g+2 (k+4, k+5)
        #pragma unroll
        for (int t = 0; t < 16; ++t)
            xA[t] = *(const float2*)(xb + (size_t)t * IN_DIM + k + 4);
        wA0 = *(const float4*)(wb + (size_t)(k + 4) * HID);
        wA1 = *(const float4*)(wb + (size_t)(k + 5) * HID);

        FMA_GROUP(xB, wB0, wB1)
        // refill B <- group g+3 (k+6, k+7)
        #pragma unroll
        for (int t = 0; t < 16; ++t)
            xB[t] = *(const float2*)(xb + (size_t)t * IN_DIM + k + 6);
        wB0 = *(const float4*)(wb + (size_t)(k + 6) * HID);
        wB1 = *(const float4*)(wb + (size_t)(k + 7) * HID);
    }
    // epilogue: groups 510 (k=1020,1021) and 511 (k=1022,1023)
    FMA_GROUP(xA, wA0, wA1)
    FMA_GROUP(xB, wB0, wB1)
#undef FMA_GROUP

    // bias + relu (lane's h = l*4 .. l*4+3)
    {
        float4 bb = *(const float4*)(b1 + l * 4);
        float bias1[4] = {bb.x, bb.y, bb.z, bb.w};
        #pragma unroll
        for (int t = 0; t < 16; ++t)
            #pragma unroll
            for (int j = 0; j < 4; ++j)
                acc[t][j] = fmaxf(acc[t][j] + bias1[j], 0.f);
    }

    // ---------------- phase B: logits = H @ W2^T + b2 (round-2 verbatim) ----
    const int ta = tid >> 4;   // 0..15 -> tokens ta*4 .. ta*4+3
    const int eb = tid & 15;   // 0..15 -> experts eb*4 .. eb*4+3

    float acc2[4][4];
    #pragma unroll
    for (int i = 0; i < 4; ++i)
        #pragma unroll
        for (int j = 0; j < 4; ++j) acc2[i][j] = 0.f;

    #pragma unroll
    for (int p = 0; p < 2; ++p) {
        // dump H half-slice: lanes with h in [p*128, p*128+128) write their
        // 16 tok x 4 hid into the same swizzled [hl][col] layout as round 2.
        if ((l >> 5) == p) {
            const int hl_base = (l & 31) * 4;
            #pragma unroll
            for (int t = 0; t < 16; ++t) {
                int tt  = w * 16 + t;
                int col = (((tt >> 2) ^ (l & 15)) << 2) | (tt & 3);
                #pragma unroll
                for (int jj = 0; jj < 4; ++jj)
                    sm.b.Hs[hl_base + jj][col] = acc[t][jj];
            }
        }
        __syncthreads();
        #pragma unroll 1
        for (int c4 = 0; c4 < 4; ++c4) {
            // stage W2 k-chunk [p*128 + c4*32, +32)
            #pragma unroll
            for (int r = 0; r < 2; ++r) {
                int slot = tid + 256 * r;
                int e  = slot >> 3, kq = (slot & 7) * 4;
                float4 v = *(const float4*)(w2 + (size_t)e * HID + p * 128 + c4 * 32 + kq);
                int col = (((e >> 2) ^ (kq >> 2)) << 2) | (e & 3);
                sm.b.W2s[kq + 0][col] = v.x;
                sm.b.W2s[kq + 1][col] = v.y;
                sm.b.W2s[kq + 2][col] = v.z;
                sm.b.W2s[kq + 3][col] = v.w;
            }
            __syncthreads();
            #pragma unroll
            for (int m = 0; m < 8; ++m) {
                const float* wbp = &sm.b.W2s[0][((eb ^ m) << 2)];
                #pragma unroll
                for (int kk = 0; kk < 4; ++kk) {
                    int k  = m * 4 + kk;
                    int hl = c4 * 32 + k;
                    float4 hv = *(const float4*)&sm.b.Hs[hl][((ta ^ ((hl >> 2) & 15)) << 2)];
                    float4 wv = *(const float4*)(wbp + k * 64);
                    float hvv[4] = {hv.x, hv.y, hv.z, hv.w};
                    float wvv[4] = {wv.x, wv.y, wv.z, wv.w};
                    #pragma unroll
                    for (int i = 0; i < 4; ++i)
                        #pragma unroll
                        for (int j = 0; j < 4; ++j)
                            acc2[i][j] = fmaf(hvv[i], wvv[j], acc2[i][j]);
                }
            }
            __syncthreads();
        }
    }

    // logits (+b2) -> Ls
    {
        float4 b2v = *(const float4*)(b2 + eb * 4);
        float bb2[4] = {b2v.x, b2v.y, b2v.z, b2v.w};
        #pragma unroll
        for (int i = 0; i < 4; ++i)
            #pragma unroll
            for (int j = 0; j < 4; ++j)
                sm.Ls[ta * 4 + i][eb * 4 + j] = acc2[i][j] + bb2[j];
    }
    __syncthreads();

    // one lane per token: top-2 (strict >, ties -> lower index, matching
    // jax.lax.top_k), then 2-way softmax.
    if (tid < 64) {
        const int t = tid;
        float m1 = -INFINITY, m2 = -INFINITY;
        int i1 = 0, i2 = 0;
        #pragma unroll 8
        for (int e = 0; e < NE; ++e) {
            float v = sm.Ls[t][e];
            if (v > m1)      { m2 = m1; i2 = i1; m1 = v; i1 = e; }
            else if (v > m2) { m2 = v; i2 = e; }
        }
        float e2  = expf(m2 - m1);           // <= 1, no overflow
        float inv = 1.f / (1.f + e2);
        int gt = t0 + t;
        out[(size_t)gt * 2 + 0] = (float)i1;
        out[(size_t)gt * 2 + 1] = (float)i2;
        out[(size_t)2 * N_TOK + (size_t)gt * 2 + 0] = inv;
        out[(size_t)2 * N_TOK + (size_t)gt * 2 + 1] = e2 * inv;
    }
}

extern "C" void kernel_launch(void* const* d_in, const int* in_sizes, int n_in,
                              void* d_out, int out_size, void* d_ws, size_t ws_size,
                              hipStream_t stream) {
    const float* x  = (const float*)d_in[0];  // [32768,1024]
    const float* w1 = (const float*)d_in[1];  // [256,1024]
    const float* b1 = (const float*)d_in[2];  // [256]
    const float* w2 = (const float*)d_in[3];  // [64,256]
    const float* b2 = (const float*)d_in[4];  // [64]
    float* out = (float*)d_out;               // 131072 floats: idx then gates
    float* w1t = (float*)d_ws;                // workspace: W1T [1024][256], 1 MB

    transpose_w1<<<dim3(32, 8), 256, 0, stream>>>(w1, w1t);
    moe_gate<<<N_TOK / 64, 256, 0, stream>>>(x, w1t, b1, w2, b2, out);
}